// Round 14
// baseline (337.054 us; speedup 1.0000x reference)
//
#include <hip/hip_runtime.h>

#define HH 8
#define NN 32
#define TT 2048
#define DD 256

typedef float f4 __attribute__((ext_vector_type(4)));
typedef float f32x4 __attribute__((ext_vector_type(4)));
typedef _Float16 f16x8 __attribute__((ext_vector_type(8)));
typedef __fp16 fp16x2 __attribute__((ext_vector_type(2)));   // cvt_pkrtz return type
typedef unsigned short u16;
typedef u16 u16x8 __attribute__((ext_vector_type(8)));

__device__ __forceinline__ u16 f2h(float x) {
  _Float16 h = (_Float16)x;
  return *(u16*)&h;
}

// Fast tanh, valid for ALL x: tanh(x) = 1 - 2/(exp(2x)+1).
__device__ __forceinline__ float ftanh(float x) {
  float e = __expf(x + x);
  float r = __builtin_amdgcn_rcpf(e + 1.f);
  return __builtin_fmaf(-2.f, r, 1.f);
}

__device__ __forceinline__ void gl_lds16(const void* g, void* l) {
  __builtin_amdgcn_global_load_lds((const __attribute__((address_space(1))) unsigned*)g,
                                   (__attribute__((address_space(3))) unsigned*)l, 16, 0, 0);
}

// ===========================================================================
// Packed Wm layout (verified R2-R13), per 8KB region = [128 rows][32 k] f16:
//   line = row>>1; slot pos = (ksl | ((row&1)<<2)) ^ (line&7);
//   u16 j in slot holds k = ks*32 + ksl*4 + {0,1,2,3,16,17,18,19}[j].
// pb [h*2+eb][ks(8)][4096 u16]  (1MB total). mk is now consumed RAW (no packA).
// ===========================================================================
__global__ void k_pack(const float* __restrict__ wm, u16* __restrict__ pb) {
  int u = blockIdx.x * 256 + threadIdx.x;   // 65,536 threads
  int pos  = u & 7;
  int line = (u >> 3) & 63;
  int ks   = (u >> 9) & 7;
  int eb   = (u >> 12) & 1;
  int h    = u >> 13;
  int origpos = pos ^ (line & 7);
  int el  = (line << 1) + (origpos >> 2);
  int e   = (eb << 7) + el;
  int ksl = origpos & 3;
  int kb  = (ks << 5) + (ksl << 2);
  const float* src = wm + (((size_t)h * 256 + e) << 8) + kb;
  f4 v0 = *(const f4*)src;
  f4 v1 = *(const f4*)(src + 16);
  u16 hv[8] = {f2h(v0.x), f2h(v0.y), f2h(v0.z), f2h(v0.w),
               f2h(v1.x), f2h(v1.y), f2h(v1.z), f2h(v1.w)};
  *(u16x8*)(pb + ((size_t)u << 3)) = *(u16x8*)hv;
}

// ---------------------------------------------------------------------------
// sc2[(h*32+n)*2+eb][t] = sum_{e in eb-half} tanh(Wm[h] @ mk[n,t])[e] * ok[n,e]
// A=Wm (M=e 128, LDS-resident all 8 ks = 64KB, staged ONCE), B=mk (N=t 128,
// streamed raw fp32 global->VGPR + in-reg cvt_pkrtz). BARRIER-FREE K-loop:
// waves free-run; cur/nxt named A-reg double buffer hides load latency.
// ---------------------------------------------------------------------------
__global__ __launch_bounds__(256, 2) void k_scoresf(
    const float* __restrict__ ok, const float* __restrict__ mk,
    const u16* __restrict__ pb, float* __restrict__ sc2) {
  __shared__ __align__(1024) u16 lds[32768];   // 64KB: Wm image [ks(8)][4096 u16]

  const int bid = blockIdx.x;
  const int h  = bid & 7;            // == XCD
  const int eb = (bid >> 3) & 1;
  const int tb = (bid >> 4) & 15;
  const int n  = bid >> 8;
  const int tid = threadIdx.x;
  const int wave = tid >> 6;
  const int lane = tid & 63;
  const int wr = wave >> 1, wc = wave & 1;   // wr: e-half, wc: t-half
  const int l15 = lane & 15, lg = lane >> 4;

  // Wm fragment LDS offsets (u16 units within one 4096-u16 ks-region)
  int Woff[4];
#pragma unroll
  for (int mi = 0; mi < 4; ++mi) {
    int row = (wr << 6) + (mi << 4) + l15;
    int line = row >> 1;
    int pos = (lg | ((row & 1) << 2)) ^ (line & 7);
    Woff[mi] = (line << 6) + (pos << 3);
  }

  // Stage ALL of Wm(h,eb) packed -> LDS (64 chunks x 1KB), once.
  const u16* bbase = pb + ((size_t)(h * 2 + eb) << 15);
#pragma unroll
  for (int i = 0; i < 16; ++i) {
    const int c = (i << 2) + wave;
    gl_lds16(bbase + (c << 9) + (lane << 3), &lds[c << 9]);
  }

  // A (mk) base pointers: 4 t-rows per lane (ni strided 16 rows = 4096 floats).
  const float* pA0 = mk + (((size_t)n * TT + (tb << 7) + (wc << 6) + l15) << 8) + (lg << 2);
  const float* pA1 = pA0 + 4096;
  const float* pA2 = pA0 + 8192;
  const float* pA3 = pA0 + 12288;

  f32x4 acc[4][4];
#pragma unroll
  for (int i = 0; i < 4; ++i)
#pragma unroll
    for (int j = 0; j < 4; ++j) acc[i][j] = (f32x4){0.f, 0.f, 0.f, 0.f};

#define LOADA(BUF, KS)                                                          \
  do {                                                                          \
    const int o = (KS) << 5;                                                    \
    BUF[0] = *(const f4*)(pA0 + o);  BUF[1] = *(const f4*)(pA0 + o + 16);       \
    BUF[2] = *(const f4*)(pA1 + o);  BUF[3] = *(const f4*)(pA1 + o + 16);       \
    BUF[4] = *(const f4*)(pA2 + o);  BUF[5] = *(const f4*)(pA2 + o + 16);       \
    BUF[6] = *(const f4*)(pA3 + o);  BUF[7] = *(const f4*)(pA3 + o + 16);       \
  } while (0)

  union F16x8 { f16x8 v; fp16x2 p[4]; };

#define COMPUTE(BUF, KS)                                                        \
  do {                                                                          \
    f16x8 mfr[4], wfr[4];                                                       \
    _Pragma("unroll") for (int ni = 0; ni < 4; ++ni) {                          \
      F16x8 m_;                                                                 \
      m_.p[0] = __builtin_amdgcn_cvt_pkrtz(BUF[2 * ni].x, BUF[2 * ni].y);       \
      m_.p[1] = __builtin_amdgcn_cvt_pkrtz(BUF[2 * ni].z, BUF[2 * ni].w);       \
      m_.p[2] = __builtin_amdgcn_cvt_pkrtz(BUF[2 * ni + 1].x, BUF[2 * ni + 1].y); \
      m_.p[3] = __builtin_amdgcn_cvt_pkrtz(BUF[2 * ni + 1].z, BUF[2 * ni + 1].w); \
      mfr[ni] = m_.v;                                                           \
    }                                                                           \
    _Pragma("unroll") for (int mi = 0; mi < 4; ++mi)                            \
        wfr[mi] = *(const f16x8*)&lds[Woff[mi] + ((KS) << 12)];                 \
    __builtin_amdgcn_s_setprio(1);                                              \
    _Pragma("unroll") for (int mi = 0; mi < 4; ++mi)                            \
        _Pragma("unroll") for (int ni = 0; ni < 4; ++ni)                        \
            acc[mi][ni] = __builtin_amdgcn_mfma_f32_16x16x32_f16(               \
                wfr[mi], mfr[ni], acc[mi][ni], 0, 0, 0);                        \
    __builtin_amdgcn_s_setprio(0);                                              \
  } while (0)

  f4 curA[8], nxtA[8];
  LOADA(curA, 0);
  __syncthreads();   // drains Wm gl_lds (vmcnt 0) + makes LDS visible

#pragma unroll 1
  for (int ks2 = 0; ks2 < 4; ++ks2) {
    const int ks = ks2 << 1;
    LOADA(nxtA, ks + 1);
    COMPUTE(curA, ks);
    if (ks2 < 3) LOADA(curA, ks + 2);
    COMPUTE(nxtA, ks + 1);
  }
#undef LOADA
#undef COMPUTE

  // Epilogue: S_partial[t] = sum_e tanh(P^T[e][t]) * ok[e] via 2nd MFMA.
  // acc lane layout: e_row = mi*16 + lg*4 + j, t_col = l15.
#pragma unroll
  for (int mi = 0; mi < 4; ++mi)
#pragma unroll
    for (int ni = 0; ni < 4; ++ni)
#pragma unroll
      for (int j = 0; j < 4; ++j) acc[mi][ni][j] = ftanh(acc[mi][ni][j]);

  F16x8 a2[2];
#pragma unroll
  for (int q = 0; q < 2; ++q) {
    const float* okb = ok + (n << 8) + (eb << 7) + (wr << 6) + (q << 5) + (lg << 2);
    a2[q].p[0] = __builtin_amdgcn_cvt_pkrtz(okb[0], okb[1]);
    a2[q].p[1] = __builtin_amdgcn_cvt_pkrtz(okb[2], okb[3]);
    a2[q].p[2] = __builtin_amdgcn_cvt_pkrtz(okb[16], okb[17]);
    a2[q].p[3] = __builtin_amdgcn_cvt_pkrtz(okb[18], okb[19]);
  }

  f32x4 d2[4];
#pragma unroll
  for (int ni = 0; ni < 4; ++ni) d2[ni] = (f32x4){0.f, 0.f, 0.f, 0.f};
#pragma unroll
  for (int ni = 0; ni < 4; ++ni) {
#pragma unroll
    for (int q = 0; q < 2; ++q) {
      F16x8 b2;
      b2.p[0] = __builtin_amdgcn_cvt_pkrtz(acc[2 * q][ni][0], acc[2 * q][ni][1]);
      b2.p[1] = __builtin_amdgcn_cvt_pkrtz(acc[2 * q][ni][2], acc[2 * q][ni][3]);
      b2.p[2] = __builtin_amdgcn_cvt_pkrtz(acc[2 * q + 1][ni][0], acc[2 * q + 1][ni][1]);
      b2.p[3] = __builtin_amdgcn_cvt_pkrtz(acc[2 * q + 1][ni][2], acc[2 * q + 1][ni][3]);
      d2[ni] = __builtin_amdgcn_mfma_f32_16x16x32_f16(a2[q].v, b2.v, d2[ni], 0, 0, 0);
    }
  }

  // red aliases the Wm LDS image -> barrier BEFORE reuse (waves are desynced).
  __syncthreads();
  float* red = (float*)&lds[0];   // [128][2]
  if (lg == 0) {
#pragma unroll
    for (int ni = 0; ni < 4; ++ni)
      red[(((wc << 6) + (ni << 4) + l15) << 1) + wr] = d2[ni][0];
  }
  __syncthreads();
  if (tid < 128) {
    float v = red[tid << 1] + red[(tid << 1) + 1];
    sc2[((size_t)((h * 32 + n) * 2 + eb) << 11) + (tb << 7) + tid] = v;
  }
}

// ---------------------------------------------------------------------------
// Softmax over T per (h,n) row: adds the two eb partials, result -> eb=0 slot.
// ---------------------------------------------------------------------------
__global__ void k_softmax(float* __restrict__ sc2) {
  __shared__ float sm[8];
  const int row = blockIdx.x, tid = threadIdx.x;
  float* b0 = sc2 + ((size_t)row << 12);
  const float* b1 = b0 + 2048;
  f4 a = *(const f4*)(b0 + tid * 8);
  f4 b = *(const f4*)(b0 + tid * 8 + 4);
  f4 a1 = *(const f4*)(b1 + tid * 8);
  f4 b1v = *(const f4*)(b1 + tid * 8 + 4);
  a.x += a1.x; a.y += a1.y; a.z += a1.z; a.w += a1.w;
  b.x += b1v.x; b.y += b1v.y; b.z += b1v.z; b.w += b1v.w;
  float m = fmaxf(fmaxf(fmaxf(a.x, a.y), fmaxf(a.z, a.w)),
                  fmaxf(fmaxf(b.x, b.y), fmaxf(b.z, b.w)));
#pragma unroll
  for (int o = 1; o < 64; o <<= 1) m = fmaxf(m, __shfl_xor(m, o));
  if ((tid & 63) == 0) sm[tid >> 6] = m;
  __syncthreads();
  m = fmaxf(fmaxf(sm[0], sm[1]), fmaxf(sm[2], sm[3]));
  a.x = __expf(a.x - m); a.y = __expf(a.y - m); a.z = __expf(a.z - m); a.w = __expf(a.w - m);
  b.x = __expf(b.x - m); b.y = __expf(b.y - m); b.z = __expf(b.z - m); b.w = __expf(b.w - m);
  float s = a.x + a.y + a.z + a.w + b.x + b.y + b.z + b.w;
#pragma unroll
  for (int o = 1; o < 64; o <<= 1) s += __shfl_xor(s, o);
  if ((tid & 63) == 0) sm[4 + (tid >> 6)] = s;
  __syncthreads();
  s = sm[4] + sm[5] + sm[6] + sm[7];
  float inv = 1.f / s;
  a.x *= inv; a.y *= inv; a.z *= inv; a.w *= inv;
  b.x *= inv; b.y *= inv; b.z *= inv; b.w *= inv;
  *(f4*)(b0 + tid * 8) = a;
  *(f4*)(b0 + tid * 8 + 4) = b;
}

// ---------------------------------------------------------------------------
// Partial rep over t-slices of 128: rp[n][sl][h*256+d]; probs at stride 4096.
// ---------------------------------------------------------------------------
__global__ void k_rep(const float* __restrict__ mv, const float* __restrict__ p,
                      float* __restrict__ rp) {
  __shared__ float pl[8][128];
  const int b = blockIdx.x;
  const int n = b >> 4, sl = b & 15;
  const int tid = threadIdx.x;
  for (int i = tid; i < 1024; i += 256) {
    int h = i >> 7, t = i & 127;
    pl[h][t] = p[(((size_t)h * 32 + n) << 12) + sl * 128 + t];
  }
  __syncthreads();
  float r[8] = {0.f, 0.f, 0.f, 0.f, 0.f, 0.f, 0.f, 0.f};
  const float* src = mv + (((size_t)n << 11) + sl * 128) * DD + tid;
#pragma unroll 4
  for (int tt = 0; tt < 128; ++tt) {
    float v = src[(size_t)tt * DD];
#pragma unroll
    for (int h = 0; h < 8; ++h) r[h] = fmaf(pl[h][tt], v, r[h]);
  }
  float* dst = rp + (((size_t)n * 16 + sl) << 11) + tid;
#pragma unroll
  for (int h = 0; h < 8; ++h) dst[h * 256] = r[h];
}

// ---------------------------------------------------------------------------
// out[n][i] = b[i] + sum_j concat[n][j] * Wo_w[i][j]
// ---------------------------------------------------------------------------
__global__ void k_out(const float* __restrict__ rp, const float* __restrict__ w,
                      const float* __restrict__ bias, float* __restrict__ out) {
  __shared__ float c[2048];
  const int n = blockIdx.x, tid = threadIdx.x;
  for (int j = tid; j < 2048; j += 256) {
    float s = 0.f;
#pragma unroll
    for (int sl = 0; sl < 16; ++sl) s += rp[(((size_t)n * 16 + sl) << 11) + j];
    c[j] = s;
  }
  __syncthreads();
  float acc = bias[tid];
  const f4* wrow = (const f4*)(w + (size_t)tid * 2048);
  const f4* cc = (const f4*)c;
  for (int j = 0; j < 512; ++j) {
    f4 wv = wrow[j];
    f4 cv = cc[j];
    acc += wv.x * cv.x + wv.y * cv.y + wv.z * cv.z + wv.w * cv.w;
  }
  out[n * 256 + tid] = acc;
}

extern "C" void kernel_launch(void* const* d_in, const int* in_sizes, int n_in,
                              void* d_out, int out_size, void* d_ws, size_t ws_size,
                              hipStream_t stream) {
  const float* ok  = (const float*)d_in[0];
  const float* mk  = (const float*)d_in[1];
  const float* mv  = (const float*)d_in[2];
  const float* wm  = (const float*)d_in[3];
  const float* wow = (const float*)d_in[4];
  const float* wob = (const float*)d_in[5];
  float* out = (float*)d_out;
  char* ws = (char*)d_ws;

  // ws: [0,4MB) sc2 partials/probs | [4,5MB) packB | [8,16MB) rep partials
  float* sc2 = (float*)ws;
  u16* pb    = (u16*)(ws + (4u << 20));
  float* rp  = (float*)(ws + (8u << 20));

  hipLaunchKernelGGL(k_pack,    dim3(256),  dim3(256), 0, stream, wm, pb);
  hipLaunchKernelGGL(k_scoresf, dim3(8192), dim3(256), 0, stream, ok, mk, pb, sc2);
  hipLaunchKernelGGL(k_softmax, dim3(256),  dim3(256), 0, stream, sc2);
  hipLaunchKernelGGL(k_rep,     dim3(512),  dim3(256), 0, stream, mv, sc2, rp);
  hipLaunchKernelGGL(k_out,     dim3(32),   dim3(256), 0, stream, rp, wow, wob, out);
}

// Round 15
// 144.447 us; speedup vs baseline: 2.3334x; 2.3334x over previous
//
#include <hip/hip_runtime.h>

#define HH 8
#define NN 32
#define TT 2048
#define DD 256

typedef float f4 __attribute__((ext_vector_type(4)));
typedef float f32x4 __attribute__((ext_vector_type(4)));
typedef _Float16 f16x8 __attribute__((ext_vector_type(8)));
typedef __fp16 fp16x2 __attribute__((ext_vector_type(2)));   // cvt_pkrtz return type
typedef unsigned short u16;
typedef u16 u16x8 __attribute__((ext_vector_type(8)));

__device__ __forceinline__ u16 f2h(float x) {
  _Float16 h = (_Float16)x;
  return *(u16*)&h;
}

// Fast tanh, valid for ALL x: tanh(x) = 1 - 2/(exp(2x)+1).
__device__ __forceinline__ float ftanh(float x) {
  float e = __expf(x + x);
  float r = __builtin_amdgcn_rcpf(e + 1.f);
  return __builtin_fmaf(-2.f, r, 1.f);
}

__device__ __forceinline__ void gl_lds16(const void* g, void* l) {
  __builtin_amdgcn_global_load_lds((const __attribute__((address_space(1))) unsigned*)g,
                                   (__attribute__((address_space(3))) unsigned*)l, 16, 0, 0);
}

// ===========================================================================
// Packed operand layout (verified R2-R13), 128-row regions:
// per 8KB region = [128 rows][32 k] f16:
//   line = row>>1 (128B lines of 8 x 16B slots), line in [0,64);
//   slot pos = (ksl | ((row&1)<<2)) ^ (line&7)   (XOR bank swizzle);
//   within slot, u16 j holds k = ks*32 + ksl*4 + {0,1,2,3,16,17,18,19}[j].
// ===========================================================================

// Merged pack: bid<8192 -> mk [N][T][D] -> pa [n*16+tb][ks(8)][4096 u16] (32MB)
//              bid>=8192 -> Wm [H][256e][256d] -> pb [h*2+eb][ks(8)][4096 u16] (1MB)
__global__ void k_pack(const float* __restrict__ mk, const float* __restrict__ wm,
                       u16* __restrict__ pa, u16* __restrict__ pb) {
  const int bid = blockIdx.x;
  if (bid < 8192) {
    int u = bid * 256 + threadIdx.x;
    int pos  = u & 7;
    int line = (u >> 3) & 63;
    int ks   = (u >> 9) & 7;
    int tb   = (u >> 12) & 15;
    int n    = u >> 16;
    int origpos = pos ^ (line & 7);
    int r   = (line << 1) + (origpos >> 2);
    int ksl = origpos & 3;
    int kb  = (ks << 5) + (ksl << 2);
    const float* src = mk + (((size_t)n * TT + (tb << 7) + r) << 8) + kb;
    f4 v0 = *(const f4*)src;
    f4 v1 = *(const f4*)(src + 16);
    u16 hv[8] = {f2h(v0.x), f2h(v0.y), f2h(v0.z), f2h(v0.w),
                 f2h(v1.x), f2h(v1.y), f2h(v1.z), f2h(v1.w)};
    *(u16x8*)(pa + ((size_t)u << 3)) = *(u16x8*)hv;
  } else {
    int u = (bid - 8192) * 256 + threadIdx.x;
    int pos  = u & 7;
    int line = (u >> 3) & 63;
    int ks   = (u >> 9) & 7;
    int eb   = (u >> 12) & 1;
    int h    = u >> 13;
    int origpos = pos ^ (line & 7);
    int el  = (line << 1) + (origpos >> 2);
    int e   = (eb << 7) + el;
    int ksl = origpos & 3;
    int kb  = (ks << 5) + (ksl << 2);
    const float* src = wm + (((size_t)h * 256 + e) << 8) + kb;
    f4 v0 = *(const f4*)src;
    f4 v1 = *(const f4*)(src + 16);
    u16 hv[8] = {f2h(v0.x), f2h(v0.y), f2h(v0.z), f2h(v0.w),
                 f2h(v1.x), f2h(v1.y), f2h(v1.z), f2h(v1.w)};
    *(u16x8*)(pb + ((size_t)u << 3)) = *(u16x8*)hv;
  }
}

// ---------------------------------------------------------------------------
// sc2[(h*32+n)*2+eb][t] = sum_{e in eb-half} tanh(Wm[h] @ mk[n,t])[e] * ok[n,e]
// A=Wm (M=e 128), B=mk (N=t 128) -> acc = P^T[e][t]; o_k dot via 2nd MFMA.
// 3-buffer depth-2 counted-vmcnt pipeline (verified R13: 91us, MfmaUtil 35%).
// ---------------------------------------------------------------------------
__global__ __launch_bounds__(256, 3) void k_scoresf(
    const float* __restrict__ ok, const u16* __restrict__ pa,
    const u16* __restrict__ pb, float* __restrict__ sc2) {
  __shared__ __align__(1024) u16 lds[3 * 8192];  // 3 bufs x (mk 8KB | Wm 8KB)
  __shared__ float red[128][2];

  const int bid = blockIdx.x;
  const int h  = bid & 7;            // == XCD
  const int eb = (bid >> 3) & 1;
  const int tb = (bid >> 4) & 15;
  const int n  = bid >> 8;
  const int tid = threadIdx.x;
  const int wave = tid >> 6;
  const int lane = tid & 63;
  const int wr = wave >> 1, wc = wave & 1;   // wr: e-half, wc: t-half
  const int l15 = lane & 15, lg = lane >> 4;

  // fragment LDS offsets (u16 units, within one 8192-u16 buffer)
  int Woff[4], Moff[4];
#pragma unroll
  for (int mi = 0; mi < 4; ++mi) {
    int row = (wr << 6) + (mi << 4) + l15;
    int line = row >> 1;
    int pos = (lg | ((row & 1) << 2)) ^ (line & 7);
    Woff[mi] = 4096 + (line << 6) + (pos << 3);
  }
#pragma unroll
  for (int ni = 0; ni < 4; ++ni) {
    int row = (wc << 6) + (ni << 4) + l15;
    int line = row >> 1;
    int pos = (lg | ((row & 1) << 2)) ^ (line & 7);
    Moff[ni] = (line << 6) + (pos << 3);
  }

  const u16* abase = pa + ((size_t)(n * 16 + tb) << 15);
  const u16* bbase = pb + ((size_t)(h * 2 + eb) << 15);

  f32x4 acc[4][4];
#pragma unroll
  for (int i = 0; i < 4; ++i)
#pragma unroll
    for (int j = 0; j < 4; ++j) acc[i][j] = (f32x4){0.f, 0.f, 0.f, 0.f};

#define STAGE(KS, BUF)                                                          \
  do {                                                                          \
    u16* dst = &lds[(BUF) << 13];                                               \
    _Pragma("unroll") for (int j = 0; j < 4; ++j) {                             \
      const int c = (j << 2) + wave;                                           \
      const u16* src = (j < 2 ? abase + ((KS) << 12) + (c << 9)                 \
                              : bbase + ((KS) << 12) + ((c - 8) << 9)) +        \
                       (lane << 3);                                             \
      gl_lds16(src, dst + (c << 9));                                            \
    }                                                                           \
  } while (0)

#define STEP(BUF, VMC)                                                          \
  do {                                                                          \
    asm volatile("s_waitcnt vmcnt(" #VMC ")" ::: "memory");                     \
    __builtin_amdgcn_s_barrier();                                               \
    __builtin_amdgcn_sched_barrier(0);                                          \
    const u16* buf = &lds[(BUF) << 13];                                         \
    f16x8 wfr[4], mfr[4];                                                       \
    _Pragma("unroll") for (int mi = 0; mi < 4; ++mi)                            \
        wfr[mi] = *(const f16x8*)(buf + Woff[mi]);                              \
    _Pragma("unroll") for (int ni = 0; ni < 4; ++ni)                            \
        mfr[ni] = *(const f16x8*)(buf + Moff[ni]);                              \
    __builtin_amdgcn_s_setprio(1);                                              \
    _Pragma("unroll") for (int mi = 0; mi < 4; ++mi)                            \
        _Pragma("unroll") for (int ni = 0; ni < 4; ++ni)                        \
            acc[mi][ni] = __builtin_amdgcn_mfma_f32_16x16x32_f16(               \
                wfr[mi], mfr[ni], acc[mi][ni], 0, 0, 0);                        \
    __builtin_amdgcn_s_setprio(0);                                              \
    __builtin_amdgcn_sched_barrier(0);                                          \
    __builtin_amdgcn_s_barrier();                                               \
  } while (0)

  STAGE(0, 0);
  STAGE(1, 1);
  STAGE(2, 2); STEP(0, 8);   // ks=0 in buf0
  STAGE(3, 0); STEP(1, 8);   // ks=1 in buf1
  STAGE(4, 1); STEP(2, 8);   // ks=2 in buf2
  STAGE(5, 2); STEP(0, 8);   // ks=3 in buf0
  STAGE(6, 0); STEP(1, 8);   // ks=4 in buf1
  STAGE(7, 1); STEP(2, 8);   // ks=5 in buf2
  STEP(0, 4);                // ks=6 in buf0
  STEP(1, 0);                // ks=7 in buf1
#undef STEP
#undef STAGE

  // Epilogue: S_partial[t] = sum_e tanh(P^T[e][t]) * ok[e] via 2nd MFMA.
  // acc lane layout: e_row = mi*16 + lg*4 + j, t_col = l15.
#pragma unroll
  for (int mi = 0; mi < 4; ++mi)
#pragma unroll
    for (int ni = 0; ni < 4; ++ni)
#pragma unroll
      for (int j = 0; j < 4; ++j) acc[mi][ni][j] = ftanh(acc[mi][ni][j]);

  union F16x8 { f16x8 v; fp16x2 p[4]; };
  F16x8 a2[2];
#pragma unroll
  for (int q = 0; q < 2; ++q) {
    const float* okb = ok + (n << 8) + (eb << 7) + (wr << 6) + (q << 5) + (lg << 2);
    a2[q].p[0] = __builtin_amdgcn_cvt_pkrtz(okb[0], okb[1]);
    a2[q].p[1] = __builtin_amdgcn_cvt_pkrtz(okb[2], okb[3]);
    a2[q].p[2] = __builtin_amdgcn_cvt_pkrtz(okb[16], okb[17]);
    a2[q].p[3] = __builtin_amdgcn_cvt_pkrtz(okb[18], okb[19]);
  }

  f32x4 d2[4];
#pragma unroll
  for (int ni = 0; ni < 4; ++ni) d2[ni] = (f32x4){0.f, 0.f, 0.f, 0.f};
#pragma unroll
  for (int ni = 0; ni < 4; ++ni) {
#pragma unroll
    for (int q = 0; q < 2; ++q) {
      F16x8 b2;
      b2.p[0] = __builtin_amdgcn_cvt_pkrtz(acc[2 * q][ni][0], acc[2 * q][ni][1]);
      b2.p[1] = __builtin_amdgcn_cvt_pkrtz(acc[2 * q][ni][2], acc[2 * q][ni][3]);
      b2.p[2] = __builtin_amdgcn_cvt_pkrtz(acc[2 * q + 1][ni][0], acc[2 * q + 1][ni][1]);
      b2.p[3] = __builtin_amdgcn_cvt_pkrtz(acc[2 * q + 1][ni][2], acc[2 * q + 1][ni][3]);
      d2[ni] = __builtin_amdgcn_mfma_f32_16x16x32_f16(a2[q].v, b2.v, d2[ni], 0, 0, 0);
    }
  }

  if (lg == 0) {
#pragma unroll
    for (int ni = 0; ni < 4; ++ni)
      red[(wc << 6) + (ni << 4) + l15][wr] = d2[ni][0];
  }
  __syncthreads();
  if (tid < 128) {
    float v = red[tid][0] + red[tid][1];
    sc2[((size_t)((h * 32 + n) * 2 + eb) << 11) + (tb << 7) + tid] = v;
  }
}

// ---------------------------------------------------------------------------
// Softmax over T per (h,n) row: adds the two eb partials, result -> eb=0 slot.
// ---------------------------------------------------------------------------
__global__ void k_softmax(float* __restrict__ sc2) {
  __shared__ float sm[8];
  const int row = blockIdx.x, tid = threadIdx.x;
  float* b0 = sc2 + ((size_t)row << 12);
  const float* b1 = b0 + 2048;
  f4 a = *(const f4*)(b0 + tid * 8);
  f4 b = *(const f4*)(b0 + tid * 8 + 4);
  f4 a1 = *(const f4*)(b1 + tid * 8);
  f4 b1v = *(const f4*)(b1 + tid * 8 + 4);
  a.x += a1.x; a.y += a1.y; a.z += a1.z; a.w += a1.w;
  b.x += b1v.x; b.y += b1v.y; b.z += b1v.z; b.w += b1v.w;
  float m = fmaxf(fmaxf(fmaxf(a.x, a.y), fmaxf(a.z, a.w)),
                  fmaxf(fmaxf(b.x, b.y), fmaxf(b.z, b.w)));
#pragma unroll
  for (int o = 1; o < 64; o <<= 1) m = fmaxf(m, __shfl_xor(m, o));
  if ((tid & 63) == 0) sm[tid >> 6] = m;
  __syncthreads();
  m = fmaxf(fmaxf(sm[0], sm[1]), fmaxf(sm[2], sm[3]));
  a.x = __expf(a.x - m); a.y = __expf(a.y - m); a.z = __expf(a.z - m); a.w = __expf(a.w - m);
  b.x = __expf(b.x - m); b.y = __expf(b.y - m); b.z = __expf(b.z - m); b.w = __expf(b.w - m);
  float s = a.x + a.y + a.z + a.w + b.x + b.y + b.z + b.w;
#pragma unroll
  for (int o = 1; o < 64; o <<= 1) s += __shfl_xor(s, o);
  if ((tid & 63) == 0) sm[4 + (tid >> 6)] = s;
  __syncthreads();
  s = sm[4] + sm[5] + sm[6] + sm[7];
  float inv = 1.f / s;
  a.x *= inv; a.y *= inv; a.z *= inv; a.w *= inv;
  b.x *= inv; b.y *= inv; b.z *= inv; b.w *= inv;
  *(f4*)(b0 + tid * 8) = a;
  *(f4*)(b0 + tid * 8 + 4) = b;
}

// ---------------------------------------------------------------------------
// Partial rep over t-slices of 128: rp[n][sl][h*256+d]; probs at stride 4096.
// R15: f4 mv loads (1KB/wave), 4-row t-split (rr) + LDS reduction.
// ---------------------------------------------------------------------------
__global__ void k_rep(const float* __restrict__ mv, const float* __restrict__ p,
                      float* __restrict__ rp) {
  __shared__ float pl[8][128];
  __shared__ f4 part[4][64][8];   // 32KB: (rr, dq, h)
  const int b = blockIdx.x;
  const int n = b >> 4, sl = b & 15;
  const int tid = threadIdx.x;
  for (int i = tid; i < 1024; i += 256) {
    int h = i >> 7, t = i & 127;
    pl[h][t] = p[(((size_t)h * 32 + n) << 12) + sl * 128 + t];
  }
  __syncthreads();
  const int dq = tid & 63, rr = tid >> 6;
  f4 r[8];
#pragma unroll
  for (int h = 0; h < 8; ++h) r[h] = (f4){0.f, 0.f, 0.f, 0.f};
  // t = tt*4 + rr, d = dq*4
  const float* src = mv + (((size_t)n * TT + sl * 128 + rr) << 8) + (dq << 2);
#pragma unroll 4
  for (int tt = 0; tt < 32; ++tt) {
    f4 v = *(const f4*)(src + tt * 1024);   // +4 rows per tt
    float w0 = 0.f;
#pragma unroll
    for (int h = 0; h < 8; ++h) {
      float pw = pl[h][(tt << 2) + rr];
      r[h].x = fmaf(pw, v.x, r[h].x);
      r[h].y = fmaf(pw, v.y, r[h].y);
      r[h].z = fmaf(pw, v.z, r[h].z);
      r[h].w = fmaf(pw, v.w, r[h].w);
    }
    (void)w0;
  }
#pragma unroll
  for (int h = 0; h < 8; ++h) part[rr][dq][h] = r[h];
  __syncthreads();
  // 512 (dq,h) outputs; 256 threads x 2
#pragma unroll
  for (int pp = 0; pp < 2; ++pp) {
    int q = tid + (pp << 8);
    int hq = q & 7, dqq = q >> 3;
    f4 s = part[0][dqq][hq];
    s.x += part[1][dqq][hq].x + part[2][dqq][hq].x + part[3][dqq][hq].x;
    s.y += part[1][dqq][hq].y + part[2][dqq][hq].y + part[3][dqq][hq].y;
    s.z += part[1][dqq][hq].z + part[2][dqq][hq].z + part[3][dqq][hq].z;
    s.w += part[1][dqq][hq].w + part[2][dqq][hq].w + part[3][dqq][hq].w;
    *(f4*)(rp + (((size_t)n * 16 + sl) << 11) + (hq << 8) + (dqq << 2)) = s;
  }
}

// ---------------------------------------------------------------------------
// out[n][i] = b[i] + sum_j concat[n][j] * Wo_w[i][j]
// R15: 256 blocks (n x 8 output-chunks of 32); 8 threads per output.
// ---------------------------------------------------------------------------
__global__ void k_out(const float* __restrict__ rp, const float* __restrict__ w,
                      const float* __restrict__ bias, float* __restrict__ out) {
  __shared__ float c[2048];
  const int b = blockIdx.x;
  const int n = b >> 3, ic = b & 7;
  const int tid = threadIdx.x;
  for (int j = tid; j < 2048; j += 256) {
    float s = 0.f;
#pragma unroll
    for (int sl = 0; sl < 16; ++sl) s += rp[(((size_t)n * 16 + sl) << 11) + j];
    c[j] = s;
  }
  __syncthreads();
  const int ii = (ic << 5) + (tid >> 3);   // output index 0..255
  const int seg = tid & 7;                 // 256-float j-segment
  const f4* wrow = (const f4*)(w + (size_t)ii * 2048 + seg * 256);
  const f4* cc = (const f4*)(c + seg * 256);
  float acc = 0.f;
#pragma unroll 8
  for (int j = 0; j < 64; ++j) {
    f4 wv = wrow[j];
    f4 cv = cc[j];
    acc += wv.x * cv.x + wv.y * cv.y + wv.z * cv.z + wv.w * cv.w;
  }
  acc += __shfl_xor(acc, 1);
  acc += __shfl_xor(acc, 2);
  acc += __shfl_xor(acc, 4);
  if (seg == 0) out[n * 256 + ii] = bias[ii] + acc;
}

extern "C" void kernel_launch(void* const* d_in, const int* in_sizes, int n_in,
                              void* d_out, int out_size, void* d_ws, size_t ws_size,
                              hipStream_t stream) {
  const float* ok  = (const float*)d_in[0];
  const float* mk  = (const float*)d_in[1];
  const float* mv  = (const float*)d_in[2];
  const float* wm  = (const float*)d_in[3];
  const float* wow = (const float*)d_in[4];
  const float* wob = (const float*)d_in[5];
  float* out = (float*)d_out;
  char* ws = (char*)d_ws;

  // ws: [0,4MB) sc2 partials/probs | [4,5MB) packB | [8,16MB) rep | [16,48MB) packA
  float* sc2 = (float*)ws;
  u16* pb    = (u16*)(ws + (4u << 20));
  float* rp  = (float*)(ws + (8u << 20));
  u16* pa    = (u16*)(ws + (16u << 20));

  hipLaunchKernelGGL(k_pack,    dim3(8448), dim3(256), 0, stream, mk, wm, pa, pb);
  hipLaunchKernelGGL(k_scoresf, dim3(8192), dim3(256), 0, stream, ok, pa, pb, sc2);
  hipLaunchKernelGGL(k_softmax, dim3(256),  dim3(256), 0, stream, sc2);
  hipLaunchKernelGGL(k_rep,     dim3(512),  dim3(256), 0, stream, mv, sc2, rp);
  hipLaunchKernelGGL(k_out,     dim3(256),  dim3(256), 0, stream, rp, wow, wob, out);
}

// Round 16
// 131.570 us; speedup vs baseline: 2.5618x; 1.0979x over previous
//
#include <hip/hip_runtime.h>

#define HH 8
#define NN 32
#define TT 2048
#define DD 256

typedef float f4 __attribute__((ext_vector_type(4)));
typedef float f32x4 __attribute__((ext_vector_type(4)));
typedef _Float16 f16x8 __attribute__((ext_vector_type(8)));
typedef __fp16 fp16x2 __attribute__((ext_vector_type(2)));   // cvt_pkrtz return type
typedef unsigned short u16;
typedef u16 u16x8 __attribute__((ext_vector_type(8)));

__device__ __forceinline__ u16 f2h(float x) {
  _Float16 h = (_Float16)x;
  return *(u16*)&h;
}

// Fast tanh, valid for ALL x: tanh(x) = 1 - 2/(exp(2x)+1).
__device__ __forceinline__ float ftanh(float x) {
  float e = __expf(x + x);
  float r = __builtin_amdgcn_rcpf(e + 1.f);
  return __builtin_fmaf(-2.f, r, 1.f);
}

// ===========================================================================
// Packed operand layout (verified R2-R15), 128-row regions:
// per 8KB region = [128 rows][32 k] f16:
//   line = row>>1 (128B lines of 8 x 16B slots), line in [0,64);
//   slot pos = (ksl | ((row&1)<<2)) ^ (line&7);
//   within slot, u16 j holds k = ks*32 + ksl*4 + {0,1,2,3,16,17,18,19}[j].
// KEY property used in R16: one MFMA fragment == one contiguous 16B at
// (region + ks*4096 + off), coalesced across the wave (1KB/fragment-load).
// ===========================================================================

// Merged pack: bid<8192 -> mk [N][T][D] -> pa [n*16+tb][ks(8)][4096 u16] (32MB)
//              bid>=8192 -> Wm [H][256e][256d] -> pb [h*2+eb][ks(8)][4096 u16] (1MB)
__global__ void k_pack(const float* __restrict__ mk, const float* __restrict__ wm,
                       u16* __restrict__ pa, u16* __restrict__ pb) {
  const int bid = blockIdx.x;
  if (bid < 8192) {
    int u = bid * 256 + threadIdx.x;
    int pos  = u & 7;
    int line = (u >> 3) & 63;
    int ks   = (u >> 9) & 7;
    int tb   = (u >> 12) & 15;
    int n    = u >> 16;
    int origpos = pos ^ (line & 7);
    int r   = (line << 1) + (origpos >> 2);
    int ksl = origpos & 3;
    int kb  = (ks << 5) + (ksl << 2);
    const float* src = mk + (((size_t)n * TT + (tb << 7) + r) << 8) + kb;
    f4 v0 = *(const f4*)src;
    f4 v1 = *(const f4*)(src + 16);
    u16 hv[8] = {f2h(v0.x), f2h(v0.y), f2h(v0.z), f2h(v0.w),
                 f2h(v1.x), f2h(v1.y), f2h(v1.z), f2h(v1.w)};
    *(u16x8*)(pa + ((size_t)u << 3)) = *(u16x8*)hv;
  } else {
    int u = (bid - 8192) * 256 + threadIdx.x;
    int pos  = u & 7;
    int line = (u >> 3) & 63;
    int ks   = (u >> 9) & 7;
    int eb   = (u >> 12) & 1;
    int h    = u >> 13;
    int origpos = pos ^ (line & 7);
    int el  = (line << 1) + (origpos >> 2);
    int e   = (eb << 7) + el;
    int ksl = origpos & 3;
    int kb  = (ks << 5) + (ksl << 2);
    const float* src = wm + (((size_t)h * 256 + e) << 8) + kb;
    f4 v0 = *(const f4*)src;
    f4 v1 = *(const f4*)(src + 16);
    u16 hv[8] = {f2h(v0.x), f2h(v0.y), f2h(v0.z), f2h(v0.w),
                 f2h(v1.x), f2h(v1.y), f2h(v1.z), f2h(v1.w)};
    *(u16x8*)(pb + ((size_t)u << 3)) = *(u16x8*)hv;
  }
}

// ---------------------------------------------------------------------------
// sc2[(h*32+n)*2+eb][t] = sum_{e in eb-half} tanh(Wm[h] @ mk[n,t])[e] * ok[n,e]
// R16: ZERO-LDS, ZERO-BARRIER all-register pipeline. Fragments loaded
// directly global->VGPR from the pre-permuted pa/pb (1 coalesced dwordx4
// per fragment). mk 3-deep (m0..m2), Wm 2-deep (w0,w1), fully unrolled.
// XCD-coherent map: all 16 sharers (8h x 2eb) of a pa region on ONE XCD.
// ---------------------------------------------------------------------------
__global__ __launch_bounds__(256, 3) void k_scoresf(
    const float* __restrict__ ok, const u16* __restrict__ pa,
    const u16* __restrict__ pb, float* __restrict__ sc2) {
  __shared__ float red[128][2];

  const int bid = blockIdx.x;
  const int r  = (bid & 7) | ((bid >> 7) << 3);   // pa region 0..511; XCD = r&7
  const int s  = (bid >> 3) & 15;                 // sharer index on this XCD
  const int h  = s & 7;
  const int eb = s >> 3;
  const int n  = r >> 4;
  const int tb = r & 15;
  const int tid = threadIdx.x;
  const int wave = tid >> 6;
  const int lane = tid & 63;
  const int wr = wave >> 1, wc = wave & 1;   // wr: e-half, wc: t-half
  const int l15 = lane & 15, lg = lane >> 4;

  // fragment offsets within one 4096-u16 ks-region (u16 units)
  int Woff[4], Moff[4];
#pragma unroll
  for (int mi = 0; mi < 4; ++mi) {
    int row = (wr << 6) + (mi << 4) + l15;
    int line = row >> 1;
    int pos = (lg | ((row & 1) << 2)) ^ (line & 7);
    Woff[mi] = (line << 6) + (pos << 3);
  }
#pragma unroll
  for (int ni = 0; ni < 4; ++ni) {
    int row = (wc << 6) + (ni << 4) + l15;
    int line = row >> 1;
    int pos = (lg | ((row & 1) << 2)) ^ (line & 7);
    Moff[ni] = (line << 6) + (pos << 3);
  }

  const u16* AB = pa + ((size_t)r << 15);               // mk region (64KB)
  const u16* BB = pb + ((size_t)(h * 2 + eb) << 15);    // Wm region (64KB)

  f32x4 acc[4][4];
#pragma unroll
  for (int i = 0; i < 4; ++i)
#pragma unroll
    for (int j = 0; j < 4; ++j) acc[i][j] = (f32x4){0.f, 0.f, 0.f, 0.f};

  f16x8 w0[4], w1[4], m0[4], m1[4], m2[4];

#define LM(BUF, KS)                                                             \
  do {                                                                          \
    _Pragma("unroll") for (int ni = 0; ni < 4; ++ni)                            \
        BUF[ni] = *(const f16x8*)(AB + ((KS) << 12) + Moff[ni]);                \
  } while (0)
#define LW(BUF, KS)                                                             \
  do {                                                                          \
    _Pragma("unroll") for (int mi = 0; mi < 4; ++mi)                            \
        BUF[mi] = *(const f16x8*)(BB + ((KS) << 12) + Woff[mi]);                \
  } while (0)
#define MM(WB, MB)                                                              \
  do {                                                                          \
    __builtin_amdgcn_s_setprio(1);                                              \
    _Pragma("unroll") for (int mi = 0; mi < 4; ++mi)                            \
        _Pragma("unroll") for (int ni = 0; ni < 4; ++ni)                        \
            acc[mi][ni] = __builtin_amdgcn_mfma_f32_16x16x32_f16(               \
                WB[mi], MB[ni], acc[mi][ni], 0, 0, 0);                          \
    __builtin_amdgcn_s_setprio(0);                                              \
  } while (0)

  LM(m0, 0); LM(m1, 1); LW(w0, 0);
  /*0*/ LM(m2, 2); LW(w1, 1); __builtin_amdgcn_sched_barrier(0); MM(w0, m0);
  /*1*/ LM(m0, 3); LW(w0, 2); __builtin_amdgcn_sched_barrier(0); MM(w1, m1);
  /*2*/ LM(m1, 4); LW(w1, 3); __builtin_amdgcn_sched_barrier(0); MM(w0, m2);
  /*3*/ LM(m2, 5); LW(w0, 4); __builtin_amdgcn_sched_barrier(0); MM(w1, m0);
  /*4*/ LM(m0, 6); LW(w1, 5); __builtin_amdgcn_sched_barrier(0); MM(w0, m1);
  /*5*/ LM(m1, 7); LW(w0, 6); __builtin_amdgcn_sched_barrier(0); MM(w1, m2);
  /*6*/            LW(w1, 7); __builtin_amdgcn_sched_barrier(0); MM(w0, m0);
  /*7*/                                                          MM(w1, m1);
#undef LM
#undef LW
#undef MM

  // Epilogue: S_partial[t] = sum_e tanh(P^T[e][t]) * ok[e] via 2nd MFMA.
  // acc lane layout: e_row = mi*16 + lg*4 + j, t_col = l15.
#pragma unroll
  for (int mi = 0; mi < 4; ++mi)
#pragma unroll
    for (int ni = 0; ni < 4; ++ni)
#pragma unroll
      for (int j = 0; j < 4; ++j) acc[mi][ni][j] = ftanh(acc[mi][ni][j]);

  union F16x8 { f16x8 v; fp16x2 p[4]; };
  F16x8 a2[2];
#pragma unroll
  for (int q = 0; q < 2; ++q) {
    const float* okb = ok + (n << 8) + (eb << 7) + (wr << 6) + (q << 5) + (lg << 2);
    a2[q].p[0] = __builtin_amdgcn_cvt_pkrtz(okb[0], okb[1]);
    a2[q].p[1] = __builtin_amdgcn_cvt_pkrtz(okb[2], okb[3]);
    a2[q].p[2] = __builtin_amdgcn_cvt_pkrtz(okb[16], okb[17]);
    a2[q].p[3] = __builtin_amdgcn_cvt_pkrtz(okb[18], okb[19]);
  }

  f32x4 d2[4];
#pragma unroll
  for (int ni = 0; ni < 4; ++ni) d2[ni] = (f32x4){0.f, 0.f, 0.f, 0.f};
#pragma unroll
  for (int ni = 0; ni < 4; ++ni) {
#pragma unroll
    for (int q = 0; q < 2; ++q) {
      F16x8 b2;
      b2.p[0] = __builtin_amdgcn_cvt_pkrtz(acc[2 * q][ni][0], acc[2 * q][ni][1]);
      b2.p[1] = __builtin_amdgcn_cvt_pkrtz(acc[2 * q][ni][2], acc[2 * q][ni][3]);
      b2.p[2] = __builtin_amdgcn_cvt_pkrtz(acc[2 * q + 1][ni][0], acc[2 * q + 1][ni][1]);
      b2.p[3] = __builtin_amdgcn_cvt_pkrtz(acc[2 * q + 1][ni][2], acc[2 * q + 1][ni][3]);
      d2[ni] = __builtin_amdgcn_mfma_f32_16x16x32_f16(a2[q].v, b2.v, d2[ni], 0, 0, 0);
    }
  }

  __syncthreads();
  if (lg == 0) {
#pragma unroll
    for (int ni = 0; ni < 4; ++ni)
      red[(wc << 6) + (ni << 4) + l15][wr] = d2[ni][0];
  }
  __syncthreads();
  if (tid < 128) {
    float v = red[tid][0] + red[tid][1];
    sc2[((size_t)((h * 32 + n) * 2 + eb) << 11) + (tb << 7) + tid] = v;
  }
}

// ---------------------------------------------------------------------------
// Softmax over T per (h,n) row: adds the two eb partials, result -> eb=0 slot.
// ---------------------------------------------------------------------------
__global__ void k_softmax(float* __restrict__ sc2) {
  __shared__ float sm[8];
  const int row = blockIdx.x, tid = threadIdx.x;
  float* b0 = sc2 + ((size_t)row << 12);
  const float* b1 = b0 + 2048;
  f4 a = *(const f4*)(b0 + tid * 8);
  f4 b = *(const f4*)(b0 + tid * 8 + 4);
  f4 a1 = *(const f4*)(b1 + tid * 8);
  f4 b1v = *(const f4*)(b1 + tid * 8 + 4);
  a.x += a1.x; a.y += a1.y; a.z += a1.z; a.w += a1.w;
  b.x += b1v.x; b.y += b1v.y; b.z += b1v.z; b.w += b1v.w;
  float m = fmaxf(fmaxf(fmaxf(a.x, a.y), fmaxf(a.z, a.w)),
                  fmaxf(fmaxf(b.x, b.y), fmaxf(b.z, b.w)));
#pragma unroll
  for (int o = 1; o < 64; o <<= 1) m = fmaxf(m, __shfl_xor(m, o));
  if ((tid & 63) == 0) sm[tid >> 6] = m;
  __syncthreads();
  m = fmaxf(fmaxf(sm[0], sm[1]), fmaxf(sm[2], sm[3]));
  a.x = __expf(a.x - m); a.y = __expf(a.y - m); a.z = __expf(a.z - m); a.w = __expf(a.w - m);
  b.x = __expf(b.x - m); b.y = __expf(b.y - m); b.z = __expf(b.z - m); b.w = __expf(b.w - m);
  float s = a.x + a.y + a.z + a.w + b.x + b.y + b.z + b.w;
#pragma unroll
  for (int o = 1; o < 64; o <<= 1) s += __shfl_xor(s, o);
  if ((tid & 63) == 0) sm[4 + (tid >> 6)] = s;
  __syncthreads();
  s = sm[4] + sm[5] + sm[6] + sm[7];
  float inv = 1.f / s;
  a.x *= inv; a.y *= inv; a.z *= inv; a.w *= inv;
  b.x *= inv; b.y *= inv; b.z *= inv; b.w *= inv;
  *(f4*)(b0 + tid * 8) = a;
  *(f4*)(b0 + tid * 8 + 4) = b;
}

// ---------------------------------------------------------------------------
// Partial rep over t-slices of 128: rp[n][sl][h*256+d]; probs at stride 4096.
// f4 mv loads (1KB/wave), 4-row t-split (rr) + LDS reduction (verified R15).
// ---------------------------------------------------------------------------
__global__ void k_rep(const float* __restrict__ mv, const float* __restrict__ p,
                      float* __restrict__ rp) {
  __shared__ float pl[8][128];
  __shared__ f4 part[4][64][8];   // 32KB: (rr, dq, h)
  const int b = blockIdx.x;
  const int n = b >> 4, sl = b & 15;
  const int tid = threadIdx.x;
  for (int i = tid; i < 1024; i += 256) {
    int h = i >> 7, t = i & 127;
    pl[h][t] = p[(((size_t)h * 32 + n) << 12) + sl * 128 + t];
  }
  __syncthreads();
  const int dq = tid & 63, rr = tid >> 6;
  f4 r[8];
#pragma unroll
  for (int h = 0; h < 8; ++h) r[h] = (f4){0.f, 0.f, 0.f, 0.f};
  const float* src = mv + (((size_t)n * TT + sl * 128 + rr) << 8) + (dq << 2);
#pragma unroll 4
  for (int tt = 0; tt < 32; ++tt) {
    f4 v = *(const f4*)(src + tt * 1024);
#pragma unroll
    for (int h = 0; h < 8; ++h) {
      float pw = pl[h][(tt << 2) + rr];
      r[h].x = fmaf(pw, v.x, r[h].x);
      r[h].y = fmaf(pw, v.y, r[h].y);
      r[h].z = fmaf(pw, v.z, r[h].z);
      r[h].w = fmaf(pw, v.w, r[h].w);
    }
  }
#pragma unroll
  for (int h = 0; h < 8; ++h) part[rr][dq][h] = r[h];
  __syncthreads();
#pragma unroll
  for (int pp = 0; pp < 2; ++pp) {
    int q = tid + (pp << 8);
    int hq = q & 7, dqq = q >> 3;
    f4 s = part[0][dqq][hq];
    s.x += part[1][dqq][hq].x + part[2][dqq][hq].x + part[3][dqq][hq].x;
    s.y += part[1][dqq][hq].y + part[2][dqq][hq].y + part[3][dqq][hq].y;
    s.z += part[1][dqq][hq].z + part[2][dqq][hq].z + part[3][dqq][hq].z;
    s.w += part[1][dqq][hq].w + part[2][dqq][hq].w + part[3][dqq][hq].w;
    *(f4*)(rp + (((size_t)n * 16 + sl) << 11) + (hq << 8) + (dqq << 2)) = s;
  }
}

// ---------------------------------------------------------------------------
// out[n][i] = b[i] + sum_j concat[n][j] * Wo_w[i][j]
// 256 blocks (n x 8 output-chunks of 32); 8 threads per output (verified R15).
// ---------------------------------------------------------------------------
__global__ void k_out(const float* __restrict__ rp, const float* __restrict__ w,
                      const float* __restrict__ bias, float* __restrict__ out) {
  __shared__ float c[2048];
  const int b = blockIdx.x;
  const int n = b >> 3, ic = b & 7;
  const int tid = threadIdx.x;
  for (int j = tid; j < 2048; j += 256) {
    float s = 0.f;
#pragma unroll
    for (int sl = 0; sl < 16; ++sl) s += rp[(((size_t)n * 16 + sl) << 11) + j];
    c[j] = s;
  }
  __syncthreads();
  const int ii = (ic << 5) + (tid >> 3);
  const int seg = tid & 7;
  const f4* wrow = (const f4*)(w + (size_t)ii * 2048 + seg * 256);
  const f4* cc = (const f4*)(c + seg * 256);
  float acc = 0.f;
#pragma unroll 8
  for (int j = 0; j < 64; ++j) {
    f4 wv = wrow[j];
    f4 cv = cc[j];
    acc += wv.x * cv.x + wv.y * cv.y + wv.z * cv.z + wv.w * cv.w;
  }
  acc += __shfl_xor(acc, 1);
  acc += __shfl_xor(acc, 2);
  acc += __shfl_xor(acc, 4);
  if (seg == 0) out[n * 256 + ii] = bias[ii] + acc;
}

extern "C" void kernel_launch(void* const* d_in, const int* in_sizes, int n_in,
                              void* d_out, int out_size, void* d_ws, size_t ws_size,
                              hipStream_t stream) {
  const float* ok  = (const float*)d_in[0];
  const float* mk  = (const float*)d_in[1];
  const float* mv  = (const float*)d_in[2];
  const float* wm  = (const float*)d_in[3];
  const float* wow = (const float*)d_in[4];
  const float* wob = (const float*)d_in[5];
  float* out = (float*)d_out;
  char* ws = (char*)d_ws;

  // ws: [0,4MB) sc2 partials/probs | [4,5MB) packB | [8,16MB) rep | [16,48MB) packA
  float* sc2 = (float*)ws;
  u16* pb    = (u16*)(ws + (4u << 20));
  float* rp  = (float*)(ws + (8u << 20));
  u16* pa    = (u16*)(ws + (16u << 20));

  hipLaunchKernelGGL(k_pack,    dim3(8448), dim3(256), 0, stream, mk, wm, pa, pb);
  hipLaunchKernelGGL(k_scoresf, dim3(8192), dim3(256), 0, stream, ok, pa, pb, sc2);
  hipLaunchKernelGGL(k_softmax, dim3(256),  dim3(256), 0, stream, sc2);
  hipLaunchKernelGGL(k_rep,     dim3(512),  dim3(256), 0, stream, mv, sc2, rp);
  hipLaunchKernelGGL(k_out,     dim3(256),  dim3(256), 0, stream, rp, wow, wob, out);
}